// Round 10
// baseline (334.710 us; speedup 1.0000x reference)
//
#include <hip/hip_runtime.h>
#include <hip/hip_fp16.h>
#include <math.h>

// GCN: h1 = relu(Agg(x@W1)+b1); h2 = relu(Agg(h1@W2)+b2); pooled = segment_mean(h2);
// out = log_softmax(relu(pooled@fc1+b)@fc2+b)
// Gather targets (GEMM outputs) fp8 e4m3 (128B/row). CSR entries = int2{src, norm}.
// Agg: 2 waves/node (4 half-waves, stride-4 edge interleave, 4-deep batches) ->
// 16 gathers in flight per node + 2x wave count. binB1 self-scans bucket bases.

#define D_FEAT 128
#define BSHIFT 9
#define BNODES 512
#define CHUNK 4096
#define CAPB 16384

using half8   = __attribute__((ext_vector_type(8))) _Float16;
using half4   = __attribute__((ext_vector_type(4))) _Float16;
using floatx4 = __attribute__((ext_vector_type(4))) float;
using floatx2 = __attribute__((ext_vector_type(2))) float;

// ---- single-pass binning: binned[b*CAPB + pos] = (dstlow<<17)|src ----
__global__ void __launch_bounds__(256) binA_kernel(const int* __restrict__ edges,
                                                   int* __restrict__ gcur,
                                                   int* __restrict__ binned, int E, int nb) {
    __shared__ int h[256];
    __shared__ int cur[256];
    __shared__ int base[256];
    int t = threadIdx.x;
    int c0 = blockIdx.x * CHUNK;
    int sv[CHUNK / 256], bv[CHUNK / 256];
    int i0 = c0 + t * (CHUNK / 256);
    if (i0 + (CHUNK / 256) <= E) {
#pragma unroll
        for (int k = 0; k < CHUNK / 256; k += 4) {
            int4 s4 = *(const int4*)&edges[i0 + k];
            int4 d4 = *(const int4*)&edges[E + i0 + k];
            bv[k + 0] = d4.x >> BSHIFT; sv[k + 0] = ((d4.x & (BNODES - 1)) << 17) | s4.x;
            bv[k + 1] = d4.y >> BSHIFT; sv[k + 1] = ((d4.y & (BNODES - 1)) << 17) | s4.y;
            bv[k + 2] = d4.z >> BSHIFT; sv[k + 2] = ((d4.z & (BNODES - 1)) << 17) | s4.z;
            bv[k + 3] = d4.w >> BSHIFT; sv[k + 3] = ((d4.w & (BNODES - 1)) << 17) | s4.w;
        }
    } else {
#pragma unroll
        for (int k = 0; k < CHUNK / 256; ++k) {
            int i = i0 + k;
            if (i < E) {
                int s = edges[i], d = edges[E + i];
                bv[k] = d >> BSHIFT;
                sv[k] = ((d & (BNODES - 1)) << 17) | s;
            } else bv[k] = -1;
        }
    }
    h[t] = 0;
    __syncthreads();
#pragma unroll
    for (int k = 0; k < CHUNK / 256; ++k)
        if (bv[k] >= 0) atomicAdd(&h[bv[k]], 1);
    __syncthreads();
    if (t < nb && h[t] > 0) base[t] = atomicAdd(&gcur[t], h[t]);
    cur[t] = 0;
    __syncthreads();
#pragma unroll
    for (int k = 0; k < CHUNK / 256; ++k)
        if (bv[k] >= 0) {
            int b = bv[k];
            int r = atomicAdd(&cur[b], 1);
            int pos = base[b] + r;
            if (pos < CAPB) binned[b * CAPB + pos] = sv[k];
        }
}

// ---- B1: per bucket: self-scan bucket bases, node hist -> dis/rowptr/gcursor ----
__global__ void __launch_bounds__(256) binB1_kernel(const int* __restrict__ binned,
                                                    const int* __restrict__ gcur,
                                                    float* __restrict__ dis,
                                                    int* __restrict__ rowptr,
                                                    int* __restrict__ gcursor,
                                                    int N, int E, int nb) {
    __shared__ int hist[BNODES];
    __shared__ int sdata[256];
    int t = threadIdx.x;
    int b = blockIdx.x;
    int node0 = b << BSHIFT;
    int cnt = gcur[b];
    // bucket base = exclusive prefix of gcur over [0, b)
    int gval = (t < nb) ? gcur[t] : 0;
    sdata[t] = gval;
    __syncthreads();
    for (int d = 1; d < 256; d <<= 1) {
        int u = (t >= d) ? sdata[t - d] : 0;
        __syncthreads();
        sdata[t] += u;
        __syncthreads();
    }
    int e0 = sdata[b] - cnt;
    __syncthreads();
    const int* bin = binned + (size_t)b * CAPB;
    hist[t] = 0; hist[t + 256] = 0;
    __syncthreads();
    for (int i = t; i < cnt; i += 256) atomicAdd(&hist[bin[i] >> 17], 1);
    __syncthreads();
    int a0 = hist[2 * t], a1 = hist[2 * t + 1];
    int pair = a0 + a1;
    sdata[t] = pair;
    __syncthreads();
    for (int d = 1; d < 256; d <<= 1) {
        int u = (t >= d) ? sdata[t - d] : 0;
        __syncthreads();
        sdata[t] += u;
        __syncthreads();
    }
    int excl = sdata[t] - pair;
    int p0 = e0 + excl, p1 = e0 + excl + a0;
    gcursor[(b << BSHIFT) + 2 * t] = p0;
    gcursor[(b << BSHIFT) + 2 * t + 1] = p1;
    int n0 = node0 + 2 * t, n1 = node0 + 2 * t + 1;
    if (n0 < N) { rowptr[n0] = p0; dis[n0] = rsqrtf((float)a0 + 1.0f); }
    if (n1 < N) { rowptr[n1] = p1; dis[n1] = rsqrtf((float)a1 + 1.0f); }
    if (b == nb - 1 && t == 0) rowptr[N] = E;
}

// ---- B2: per bucket: scatter csr int2{src, norm=dis[s]*dis[d]} ----
__global__ void __launch_bounds__(256) binB2_kernel(const int* __restrict__ binned,
                                                    const int* __restrict__ gcur,
                                                    const int* __restrict__ gcursor,
                                                    const float* __restrict__ dis,
                                                    int2* __restrict__ csr,
                                                    int N, int nb) {
    __shared__ int cur[BNODES];
    __shared__ float dloc[BNODES];
    int t = threadIdx.x;
    int b = blockIdx.x;
    int node0 = b << BSHIFT;
    int cnt = gcur[b];
    const int* bin = binned + (size_t)b * CAPB;
#pragma unroll
    for (int i = 0; i < 2; ++i) {
        int idx = t + i * 256;
        cur[idx] = gcursor[(b << BSHIFT) + idx];
        int n = node0 + idx;
        dloc[idx] = (n < N) ? dis[n] : 0.f;
    }
    __syncthreads();
    for (int i = t; i < cnt; i += 256) {
        int v = bin[i];
        int dstl = v >> 17, s = v & 0x1FFFF;
        int p = atomicAdd(&cur[dstl], 1);
        float nrm = dis[s] * dloc[dstl];
        csr[p] = make_int2(s, __float_as_int(nrm));
    }
}

// W transpose + fp32->fp16
__global__ void wprep_kernel(const float* __restrict__ W1, const float* __restrict__ W2,
                             _Float16* __restrict__ Wt1, _Float16* __restrict__ Wt2) {
    int i = blockIdx.x * blockDim.x + threadIdx.x;
    int n = i >> 7, k = i & 127;
    Wt1[i] = (_Float16)W1[k * 128 + n];
    Wt2[i] = (_Float16)W2[k * 128 + n];
}

// Y8[N,128] = fp8_e4m3( X[N,128] @ W[128,128] ) via fp16 MFMA.
template <bool HALF_IN>
__global__ void __launch_bounds__(256) gemm_mfma_kernel(const void* __restrict__ Xv,
                                                        const _Float16* __restrict__ WtG,
                                                        unsigned char* __restrict__ Y8, int N) {
    __shared__ _Float16 wt[128][136];
    int t = threadIdx.x;
    int row0 = blockIdx.x * 64;

#pragma unroll
    for (int i = 0; i < 8; ++i) {
        int c = t + i * 256;
        int r = c >> 4, c8 = (c & 15) * 8;
        *(half8*)&wt[r][c8] = *(const half8*)&WtG[r * 128 + c8];
    }

    int wave = t >> 6, lane = t & 63;
    int m = lane & 15, quad = lane >> 4;
    int grow = row0 + wave * 16 + m;

    half8 a[4];
    if (grow < N) {
        if (HALF_IN) {
            const _Float16* Xp = (const _Float16*)Xv;
#pragma unroll
            for (int k = 0; k < 4; ++k)
                a[k] = *(const half8*)&Xp[(size_t)grow * 128 + k * 32 + quad * 8];
        } else {
            const float* Xp = (const float*)Xv;
#pragma unroll
            for (int k = 0; k < 4; ++k) {
                float4 v0 = *(const float4*)&Xp[(size_t)grow * 128 + k * 32 + quad * 8];
                float4 v1 = *(const float4*)&Xp[(size_t)grow * 128 + k * 32 + quad * 8 + 4];
                a[k] = (half8){(_Float16)v0.x, (_Float16)v0.y, (_Float16)v0.z, (_Float16)v0.w,
                               (_Float16)v1.x, (_Float16)v1.y, (_Float16)v1.z, (_Float16)v1.w};
            }
        }
    } else {
#pragma unroll
        for (int k = 0; k < 4; ++k) a[k] = (half8){};
    }
    __syncthreads();

    floatx4 acc[8];
#pragma unroll
    for (int nt = 0; nt < 8; ++nt) acc[nt] = (floatx4){0.f, 0.f, 0.f, 0.f};
#pragma unroll
    for (int nt = 0; nt < 8; ++nt) {
#pragma unroll
        for (int k = 0; k < 4; ++k) {
            half8 bfr = *(const half8*)&wt[nt * 16 + m][k * 32 + quad * 8];
            acc[nt] = __builtin_amdgcn_mfma_f32_16x16x32_f16(a[k], bfr, acc[nt], 0, 0, 0);
        }
    }
#pragma unroll
    for (int nt = 0; nt < 8; ++nt) {
#pragma unroll
        for (int r = 0; r < 4; ++r) {
            int row = row0 + wave * 16 + quad * 4 + r;
            if (row < N) {
                float v = acc[nt][r];
                unsigned char q =
                    (unsigned char)(__builtin_amdgcn_cvt_pk_fp8_f32(v, v, 0, false) & 0xff);
                Y8[(size_t)row * 128 + nt * 16 + m] = q;
            }
        }
    }
}

// 2 waves per dst node; 4 half-waves interleave the edge list stride-4, 4-deep batches.
// Combine: shfl within wave, LDS across the node's 2 waves.
__global__ void __launch_bounds__(256) agg_kernel(const unsigned char* __restrict__ H8,
                                                  const int* __restrict__ rowptr,
                                                  const int2* __restrict__ csr,
                                                  const float* __restrict__ dis,
                                                  const float* __restrict__ bias,
                                                  _Float16* __restrict__ out, int N) {
    __shared__ float4 part[64];  // [nd*32 + sl]
    int t = threadIdx.x;
    int wave = t >> 6, lane = t & 63;
    int nd = wave >> 1, wv = wave & 1;
    int v = blockIdx.x * 2 + nd;
    int half = lane >> 5, sl = lane & 31;
    bool valid = (v < N);
    unsigned fo = (unsigned)(sl << 2);

    floatx2 a01 = {0.f, 0.f}, a23 = {0.f, 0.f};
    int r0 = 0, r1 = 0;
    if (valid) {
        r0 = rowptr[v];
        r1 = rowptr[v + 1];
        float dv = dis[v];
        {   // self loop: each of the 4 half-waves adds 0.25*dv^2*row_v
            float wself = 0.25f * dv * dv;
            unsigned int u = *(const unsigned int*)(H8 + (((unsigned)v << 7) | fo));
            floatx2 lo = __builtin_amdgcn_cvt_pk_f32_fp8(u, false);
            floatx2 hi = __builtin_amdgcn_cvt_pk_f32_fp8(u, true);
            floatx2 w2 = {wself, wself};
            a01 = w2 * lo;
            a23 = w2 * hi;
        }
#define ACC(uu, ww)                                                     \
        {                                                               \
            floatx2 lo = __builtin_amdgcn_cvt_pk_f32_fp8(uu, false);    \
            floatx2 hi = __builtin_amdgcn_cvt_pk_f32_fp8(uu, true);     \
            floatx2 w2 = {(ww), (ww)};                                  \
            a01 += w2 * lo;                                             \
            a23 += w2 * hi;                                             \
        }
        int e = r0 + wv * 2 + half;   // this half-wave's lane in the stride-4 interleave
        for (; e + 12 < r1; e += 16) {  // 4 edges per half-wave, unpredicated
            int2 c0 = csr[e], c1 = csr[e + 4], c2 = csr[e + 8], c3 = csr[e + 12];
            unsigned int u0 = *(const unsigned int*)(H8 + (((unsigned)c0.x << 7) | fo));
            unsigned int u1 = *(const unsigned int*)(H8 + (((unsigned)c1.x << 7) | fo));
            unsigned int u2 = *(const unsigned int*)(H8 + (((unsigned)c2.x << 7) | fo));
            unsigned int u3 = *(const unsigned int*)(H8 + (((unsigned)c3.x << 7) | fo));
            ACC(u0, __int_as_float(c0.y)) ACC(u1, __int_as_float(c1.y))
            ACC(u2, __int_as_float(c2.y)) ACC(u3, __int_as_float(c3.y))
        }
        if (e < r1) {   // one predicated 4-batch: clamped indices, masked weights
            int last = r1 - 1;
            int2 cc[4];
            unsigned int uu[4];
            float ww[4];
#pragma unroll
            for (int k = 0; k < 4; ++k) {
                int idx = e + 4 * k;
                cc[k] = csr[idx < last ? idx : last];
                ww[k] = (idx < r1) ? __int_as_float(cc[k].y) : 0.f;
            }
#pragma unroll
            for (int k = 0; k < 4; ++k)
                uu[k] = *(const unsigned int*)(H8 + (((unsigned)cc[k].x << 7) | fo));
#pragma unroll
            for (int k = 0; k < 4; ++k) ACC(uu[k], ww[k])
        }
#undef ACC
        // combine halves within wave
        a01[0] += __shfl_xor(a01[0], 32, 64);
        a01[1] += __shfl_xor(a01[1], 32, 64);
        a23[0] += __shfl_xor(a23[0], 32, 64);
        a23[1] += __shfl_xor(a23[1], 32, 64);
    }
    // cross-wave combine via LDS
    if (valid && wv == 1 && half == 0)
        part[nd * 32 + sl] = make_float4(a01[0], a01[1], a23[0], a23[1]);
    __syncthreads();
    if (valid && wv == 0 && half == 0) {
        float4 p = part[nd * 32 + sl];
        float4 b = *(const float4*)&bias[sl * 4];
        half4 o = {(_Float16)fmaxf(a01[0] + p.x + b.x, 0.f),
                   (_Float16)fmaxf(a01[1] + p.y + b.y, 0.f),
                   (_Float16)fmaxf(a23[0] + p.z + b.z, 0.f),
                   (_Float16)fmaxf(a23[1] + p.w + b.w, 0.f)};
        *(half4*)&out[(size_t)v * 128 + sl * 4] = o;
    }
}

__device__ __forceinline__ int lower_bound_i(const int* a, int n, int key) {
    int lo = 0, hi = n;
    while (lo < hi) {
        int mid = (lo + hi) >> 1;
        if (a[mid] < key) lo = mid + 1;
        else hi = mid;
    }
    return lo;
}

// one block (512 thr) per graph; 4 row-groups in parallel + LDS reduce
__global__ void __launch_bounds__(512) pool_kernel(const _Float16* __restrict__ H,
                                                   const int* __restrict__ batch,
                                                   float* __restrict__ pooled, int N) {
    __shared__ int range[2];
    __shared__ float part[4][128];
    int g = blockIdx.x;
    int t = threadIdx.x;
    int j = t & 127, rg = t >> 7;
    if (t < 2) range[t] = lower_bound_i(batch, N, g + t);
    __syncthreads();
    int lo = range[0], hi = range[1];
    float s = 0.f;
    for (int v = lo + rg; v < hi; v += 4) s += (float)H[(size_t)v * 128 + j];
    part[rg][j] = s;
    __syncthreads();
    if (rg == 0) {
        float tot = part[0][j] + part[1][j] + part[2][j] + part[3][j];
        pooled[g * 128 + j] = tot / fmaxf((float)(hi - lo), 1.0f);
    }
}

// one block (128 thr) per graph: relu(pooled@fc1+b1) @ fc2 + b2 -> log_softmax(2)
__global__ void head_kernel(const float* __restrict__ pooled, const float* __restrict__ fc1w,
                            const float* __restrict__ fc1b, const float* __restrict__ fc2w,
                            const float* __restrict__ fc2b, float* __restrict__ out) {
    __shared__ float p[128];
    __shared__ float r0[128], r1[128];
    int g = blockIdx.x;
    int j = threadIdx.x;
    p[j] = pooled[g * 128 + j];
    __syncthreads();
    float acc = fc1b[j];
#pragma unroll 8
    for (int k = 0; k < 128; ++k) acc = fmaf(p[k], fc1w[k * 128 + j], acc);
    float gv = fmaxf(acc, 0.f);
    r0[j] = gv * fc2w[j * 2 + 0];
    r1[j] = gv * fc2w[j * 2 + 1];
    __syncthreads();
    for (int s = 64; s > 0; s >>= 1) {
        if (j < s) {
            r0[j] += r0[j + s];
            r1[j] += r1[j + s];
        }
        __syncthreads();
    }
    if (j == 0) {
        float l0 = r0[0] + fc2b[0];
        float l1 = r1[0] + fc2b[1];
        float m = fmaxf(l0, l1);
        float lse = m + logf(expf(l0 - m) + expf(l1 - m));
        out[g * 2 + 0] = l0 - lse;
        out[g * 2 + 1] = l1 - lse;
    }
}

extern "C" void kernel_launch(void* const* d_in, const int* in_sizes, int n_in,
                              void* d_out, int out_size, void* d_ws, size_t ws_size,
                              hipStream_t stream) {
    const float* x    = (const float*)d_in[0];
    const int* edges  = (const int*)d_in[1];
    const int* batch  = (const int*)d_in[2];
    const float* W1   = (const float*)d_in[3];
    const float* b1   = (const float*)d_in[4];
    const float* W2   = (const float*)d_in[5];
    const float* b2   = (const float*)d_in[6];
    const float* fc1w = (const float*)d_in[7];
    const float* fc1b = (const float*)d_in[8];
    const float* fc2w = (const float*)d_in[9];
    const float* fc2b = (const float*)d_in[10];
    float* out = (float*)d_out;

    int N = in_sizes[2];        // 100000
    int E = in_sizes[1] / 2;    // 1600000
    int G = out_size / 2;       // 1024
    int nb = (N + BNODES - 1) / BNODES;   // 196
    int nA = (E + CHUNK - 1) / CHUNK;     // 391

    char* ws = (char*)d_ws;
    size_t off = 0;
    auto alloc = [&](size_t bytes) -> char* {
        char* ptr = ws + off;
        off += (bytes + 255) & ~(size_t)255;
        return ptr;
    };
    int* gcur          = (int*)alloc((size_t)nb * 4);
    int* binned        = (int*)alloc((size_t)nb * CAPB * 4);
    int* rowptr        = (int*)alloc((size_t)(N + 1) * 4);
    float* dis         = (float*)alloc((size_t)N * 4);
    int* gcursor       = (int*)alloc((size_t)nb * BNODES * 4);
    int2* csr          = (int2*)alloc((size_t)E * 8);
    _Float16* Wt1      = (_Float16*)alloc(128 * 128 * 2);
    _Float16* Wt2      = (_Float16*)alloc(128 * 128 * 2);
    unsigned char* buf8 = (unsigned char*)alloc((size_t)N * D_FEAT);
    _Float16* bufH     = (_Float16*)alloc((size_t)N * D_FEAT * 2);
    float* pooled      = (float*)alloc((size_t)G * D_FEAT * 4);

    hipMemsetAsync(gcur, 0, (size_t)nb * 4, stream);

    binA_kernel<<<nA, 256, 0, stream>>>(edges, gcur, binned, E, nb);
    binB1_kernel<<<nb, 256, 0, stream>>>(binned, gcur, dis, rowptr, gcursor, N, E, nb);
    binB2_kernel<<<nb, 256, 0, stream>>>(binned, gcur, gcursor, dis, csr, N, nb);
    wprep_kernel<<<64, 256, 0, stream>>>(W1, W2, Wt1, Wt2);

    int gAgg = (N + 1) / 2;
    int gGemm = (N + 63) / 64;
    gemm_mfma_kernel<false><<<gGemm, 256, 0, stream>>>((const void*)x, Wt1, buf8, N);
    agg_kernel<<<gAgg, 256, 0, stream>>>(buf8, rowptr, csr, dis, b1, bufH, N);
    gemm_mfma_kernel<true><<<gGemm, 256, 0, stream>>>((const void*)bufH, Wt2, buf8, N);
    agg_kernel<<<gAgg, 256, 0, stream>>>(buf8, rowptr, csr, dis, b2, bufH, N);
    pool_kernel<<<G, 512, 0, stream>>>(bufH, batch, pooled, N);
    head_kernel<<<G, 128, 0, stream>>>(pooled, fc1w, fc1b, fc2w, fc2b, out);
}

// Round 11
// 282.026 us; speedup vs baseline: 1.1868x; 1.1868x over previous
//
#include <hip/hip_runtime.h>
#include <hip/hip_fp16.h>
#include <math.h>

// GCN: h1 = relu(Agg(x@W1)+b1); h2 = relu(Agg(h1@W2)+b2); pooled = segment_mean(h2);
// out = log_softmax(relu(pooled@fc1+b)@fc2+b)
// KEY FACTORIZATION: gemm epilogue writes buf8[s] = fp8(dis[s] * h[s]); then
// Agg(v) = relu( dis[v] * (row'_v + sum_s row'_s) + bias ) -- per-edge work is a
// plain packed add, csr entry is 4B. Agg: 1 wave/node, 8 edges/half-wave batches
// + one predicated 8-tail (round-9 structure; round-10's 2-wave split regressed).

#define D_FEAT 128
#define BSHIFT 9
#define BNODES 512
#define CHUNK 4096
#define CAPB 16384

using half8   = __attribute__((ext_vector_type(8))) _Float16;
using half4   = __attribute__((ext_vector_type(4))) _Float16;
using floatx4 = __attribute__((ext_vector_type(4))) float;
using floatx2 = __attribute__((ext_vector_type(2))) float;

// ---- single-pass binning: binned[b*CAPB + pos] = (dstlow<<17)|src ----
__global__ void __launch_bounds__(256) binA_kernel(const int* __restrict__ edges,
                                                   int* __restrict__ gcur,
                                                   int* __restrict__ binned, int E, int nb) {
    __shared__ int h[256];
    __shared__ int cur[256];
    __shared__ int base[256];
    int t = threadIdx.x;
    int c0 = blockIdx.x * CHUNK;
    int sv[CHUNK / 256], bv[CHUNK / 256];
    int i0 = c0 + t * (CHUNK / 256);
    if (i0 + (CHUNK / 256) <= E) {
#pragma unroll
        for (int k = 0; k < CHUNK / 256; k += 4) {
            int4 s4 = *(const int4*)&edges[i0 + k];
            int4 d4 = *(const int4*)&edges[E + i0 + k];
            bv[k + 0] = d4.x >> BSHIFT; sv[k + 0] = ((d4.x & (BNODES - 1)) << 17) | s4.x;
            bv[k + 1] = d4.y >> BSHIFT; sv[k + 1] = ((d4.y & (BNODES - 1)) << 17) | s4.y;
            bv[k + 2] = d4.z >> BSHIFT; sv[k + 2] = ((d4.z & (BNODES - 1)) << 17) | s4.z;
            bv[k + 3] = d4.w >> BSHIFT; sv[k + 3] = ((d4.w & (BNODES - 1)) << 17) | s4.w;
        }
    } else {
#pragma unroll
        for (int k = 0; k < CHUNK / 256; ++k) {
            int i = i0 + k;
            if (i < E) {
                int s = edges[i], d = edges[E + i];
                bv[k] = d >> BSHIFT;
                sv[k] = ((d & (BNODES - 1)) << 17) | s;
            } else bv[k] = -1;
        }
    }
    h[t] = 0;
    __syncthreads();
#pragma unroll
    for (int k = 0; k < CHUNK / 256; ++k)
        if (bv[k] >= 0) atomicAdd(&h[bv[k]], 1);
    __syncthreads();
    if (t < nb && h[t] > 0) base[t] = atomicAdd(&gcur[t], h[t]);
    cur[t] = 0;
    __syncthreads();
#pragma unroll
    for (int k = 0; k < CHUNK / 256; ++k)
        if (bv[k] >= 0) {
            int b = bv[k];
            int r = atomicAdd(&cur[b], 1);
            int pos = base[b] + r;
            if (pos < CAPB) binned[b * CAPB + pos] = sv[k];
        }
}

// ---- B1: per bucket: self-scan bucket bases, node hist -> dis/rowptr/gcursor ----
__global__ void __launch_bounds__(256) binB1_kernel(const int* __restrict__ binned,
                                                    const int* __restrict__ gcur,
                                                    float* __restrict__ dis,
                                                    int* __restrict__ rowptr,
                                                    int* __restrict__ gcursor,
                                                    int N, int E, int nb) {
    __shared__ int hist[BNODES];
    __shared__ int sdata[256];
    int t = threadIdx.x;
    int b = blockIdx.x;
    int node0 = b << BSHIFT;
    int cnt = gcur[b];
    int gval = (t < nb) ? gcur[t] : 0;
    sdata[t] = gval;
    __syncthreads();
    for (int d = 1; d < 256; d <<= 1) {
        int u = (t >= d) ? sdata[t - d] : 0;
        __syncthreads();
        sdata[t] += u;
        __syncthreads();
    }
    int e0 = sdata[b] - cnt;
    __syncthreads();
    const int* bin = binned + (size_t)b * CAPB;
    hist[t] = 0; hist[t + 256] = 0;
    __syncthreads();
    for (int i = t; i < cnt; i += 256) atomicAdd(&hist[bin[i] >> 17], 1);
    __syncthreads();
    int a0 = hist[2 * t], a1 = hist[2 * t + 1];
    int pair = a0 + a1;
    sdata[t] = pair;
    __syncthreads();
    for (int d = 1; d < 256; d <<= 1) {
        int u = (t >= d) ? sdata[t - d] : 0;
        __syncthreads();
        sdata[t] += u;
        __syncthreads();
    }
    int excl = sdata[t] - pair;
    int p0 = e0 + excl, p1 = e0 + excl + a0;
    gcursor[(b << BSHIFT) + 2 * t] = p0;
    gcursor[(b << BSHIFT) + 2 * t + 1] = p1;
    int n0 = node0 + 2 * t, n1 = node0 + 2 * t + 1;
    if (n0 < N) { rowptr[n0] = p0; dis[n0] = rsqrtf((float)a0 + 1.0f); }
    if (n1 < N) { rowptr[n1] = p1; dis[n1] = rsqrtf((float)a1 + 1.0f); }
    if (b == nb - 1 && t == 0) rowptr[N] = E;
}

// ---- B2: per bucket: scatter csr[p] = src (4B; norm folded into buf8 pre-scaling) ----
__global__ void __launch_bounds__(256) binB2_kernel(const int* __restrict__ binned,
                                                    const int* __restrict__ gcur,
                                                    const int* __restrict__ gcursor,
                                                    int* __restrict__ csr, int nb) {
    __shared__ int cur[BNODES];
    int t = threadIdx.x;
    int b = blockIdx.x;
    int cnt = gcur[b];
    const int* bin = binned + (size_t)b * CAPB;
    cur[t] = gcursor[(b << BSHIFT) + t];
    cur[t + 256] = gcursor[(b << BSHIFT) + t + 256];
    __syncthreads();
    for (int i = t; i < cnt; i += 256) {
        int v = bin[i];
        int p = atomicAdd(&cur[v >> 17], 1);
        csr[p] = v & 0x1FFFF;
    }
}

// W transpose + fp32->fp16
__global__ void wprep_kernel(const float* __restrict__ W1, const float* __restrict__ W2,
                             _Float16* __restrict__ Wt1, _Float16* __restrict__ Wt2) {
    int i = blockIdx.x * blockDim.x + threadIdx.x;
    int n = i >> 7, k = i & 127;
    Wt1[i] = (_Float16)W1[k * 128 + n];
    Wt2[i] = (_Float16)W2[k * 128 + n];
}

// Y8[row,:] = fp8_e4m3( dis[row] * (X[row,:] @ W) ) via fp16 MFMA.
template <bool HALF_IN>
__global__ void __launch_bounds__(256) gemm_mfma_kernel(const void* __restrict__ Xv,
                                                        const _Float16* __restrict__ WtG,
                                                        const float* __restrict__ dis,
                                                        unsigned char* __restrict__ Y8, int N) {
    __shared__ _Float16 wt[128][136];
    int t = threadIdx.x;
    int row0 = blockIdx.x * 64;

#pragma unroll
    for (int i = 0; i < 8; ++i) {
        int c = t + i * 256;
        int r = c >> 4, c8 = (c & 15) * 8;
        *(half8*)&wt[r][c8] = *(const half8*)&WtG[r * 128 + c8];
    }

    int wave = t >> 6, lane = t & 63;
    int m = lane & 15, quad = lane >> 4;
    int grow = row0 + wave * 16 + m;

    half8 a[4];
    if (grow < N) {
        if (HALF_IN) {
            const _Float16* Xp = (const _Float16*)Xv;
#pragma unroll
            for (int k = 0; k < 4; ++k)
                a[k] = *(const half8*)&Xp[(size_t)grow * 128 + k * 32 + quad * 8];
        } else {
            const float* Xp = (const float*)Xv;
#pragma unroll
            for (int k = 0; k < 4; ++k) {
                float4 v0 = *(const float4*)&Xp[(size_t)grow * 128 + k * 32 + quad * 8];
                float4 v1 = *(const float4*)&Xp[(size_t)grow * 128 + k * 32 + quad * 8 + 4];
                a[k] = (half8){(_Float16)v0.x, (_Float16)v0.y, (_Float16)v0.z, (_Float16)v0.w,
                               (_Float16)v1.x, (_Float16)v1.y, (_Float16)v1.z, (_Float16)v1.w};
            }
        }
    } else {
#pragma unroll
        for (int k = 0; k < 4; ++k) a[k] = (half8){};
    }
    __syncthreads();

    floatx4 acc[8];
#pragma unroll
    for (int nt = 0; nt < 8; ++nt) acc[nt] = (floatx4){0.f, 0.f, 0.f, 0.f};
#pragma unroll
    for (int nt = 0; nt < 8; ++nt) {
#pragma unroll
        for (int k = 0; k < 4; ++k) {
            half8 bfr = *(const half8*)&wt[nt * 16 + m][k * 32 + quad * 8];
            acc[nt] = __builtin_amdgcn_mfma_f32_16x16x32_f16(a[k], bfr, acc[nt], 0, 0, 0);
        }
    }
    int orow = row0 + wave * 16 + quad * 4;
#pragma unroll
    for (int r = 0; r < 4; ++r) {
        int row = orow + r;
        if (row < N) {
            float dr = dis[row];
#pragma unroll
            for (int nt = 0; nt < 8; ++nt) {
                float v = acc[nt][r] * dr;
                unsigned char q =
                    (unsigned char)(__builtin_amdgcn_cvt_pk_fp8_f32(v, v, 0, false) & 0xff);
                Y8[(size_t)row * 128 + nt * 16 + m] = q;
            }
        }
    }
}

// One wave per dst node over pre-scaled fp8 rows; half-wave per edge, plain adds.
// Main loop: 8 edges/half unpredicated; tail: ONE predicated 8-batch (clamped, zeroed).
__global__ void __launch_bounds__(256) agg_kernel(const unsigned char* __restrict__ H8,
                                                  const int* __restrict__ rowptr,
                                                  const int* __restrict__ csr,
                                                  const float* __restrict__ dis,
                                                  const float* __restrict__ bias,
                                                  _Float16* __restrict__ out, int N) {
    int v = (blockIdx.x * blockDim.x + threadIdx.x) >> 6;
    int lane = threadIdx.x & 63;
    if (v >= N) return;
    int half = lane >> 5, sl = lane & 31;
    int r0 = rowptr[v], r1 = rowptr[v + 1];
    float dv = dis[v];
    unsigned fo = (unsigned)(sl << 2);

    floatx2 a01, a23;
    {   // self row (pre-scaled): each half adds 0.5x, sums to 1x after combine
        unsigned int u = *(const unsigned int*)(H8 + (((unsigned)v << 7) | fo));
        floatx2 lo = __builtin_amdgcn_cvt_pk_f32_fp8(u, false);
        floatx2 hi = __builtin_amdgcn_cvt_pk_f32_fp8(u, true);
        floatx2 hf = {0.5f, 0.5f};
        a01 = hf * lo;
        a23 = hf * hi;
    }
#define ACC(uu)                                                         \
        {                                                               \
            a01 += __builtin_amdgcn_cvt_pk_f32_fp8(uu, false);          \
            a23 += __builtin_amdgcn_cvt_pk_f32_fp8(uu, true);           \
        }
#define ACCW(uu, ww)                                                    \
        {                                                               \
            floatx2 w2 = {(ww), (ww)};                                  \
            a01 += w2 * __builtin_amdgcn_cvt_pk_f32_fp8(uu, false);     \
            a23 += w2 * __builtin_amdgcn_cvt_pk_f32_fp8(uu, true);      \
        }
    int e = r0 + half;
    for (; e + 14 < r1; e += 16) {   // 8 edges per half, unpredicated, plain adds
        int s0 = csr[e],      s1 = csr[e + 2],  s2 = csr[e + 4],  s3 = csr[e + 6];
        int s4 = csr[e + 8],  s5 = csr[e + 10], s6 = csr[e + 12], s7 = csr[e + 14];
        unsigned int u0 = *(const unsigned int*)(H8 + (((unsigned)s0 << 7) | fo));
        unsigned int u1 = *(const unsigned int*)(H8 + (((unsigned)s1 << 7) | fo));
        unsigned int u2 = *(const unsigned int*)(H8 + (((unsigned)s2 << 7) | fo));
        unsigned int u3 = *(const unsigned int*)(H8 + (((unsigned)s3 << 7) | fo));
        unsigned int u4 = *(const unsigned int*)(H8 + (((unsigned)s4 << 7) | fo));
        unsigned int u5 = *(const unsigned int*)(H8 + (((unsigned)s5 << 7) | fo));
        unsigned int u6 = *(const unsigned int*)(H8 + (((unsigned)s6 << 7) | fo));
        unsigned int u7 = *(const unsigned int*)(H8 + (((unsigned)s7 << 7) | fo));
        ACC(u0) ACC(u1) ACC(u2) ACC(u3) ACC(u4) ACC(u5) ACC(u6) ACC(u7)
    }
    if (e < r1) {   // one predicated 8-batch: clamped indices, masked weights
        int last = r1 - 1;
        int ss[8];
        unsigned int uu[8];
        float ww[8];
#pragma unroll
        for (int k = 0; k < 8; ++k) {
            int idx = e + 2 * k;
            ss[k] = csr[idx < last ? idx : last];
            ww[k] = (idx < r1) ? 1.f : 0.f;
        }
#pragma unroll
        for (int k = 0; k < 8; ++k)
            uu[k] = *(const unsigned int*)(H8 + (((unsigned)ss[k] << 7) | fo));
#pragma unroll
        for (int k = 0; k < 8; ++k) ACCW(uu[k], ww[k])
    }
#undef ACC
#undef ACCW
    a01[0] += __shfl_xor(a01[0], 32, 64);
    a01[1] += __shfl_xor(a01[1], 32, 64);
    a23[0] += __shfl_xor(a23[0], 32, 64);
    a23[1] += __shfl_xor(a23[1], 32, 64);
    if (half == 0) {
        float4 b = *(const float4*)&bias[sl * 4];
        half4 o = {(_Float16)fmaxf(dv * a01[0] + b.x, 0.f),
                   (_Float16)fmaxf(dv * a01[1] + b.y, 0.f),
                   (_Float16)fmaxf(dv * a23[0] + b.z, 0.f),
                   (_Float16)fmaxf(dv * a23[1] + b.w, 0.f)};
        *(half4*)&out[(size_t)v * 128 + sl * 4] = o;
    }
}

__device__ __forceinline__ int lower_bound_i(const int* a, int n, int key) {
    int lo = 0, hi = n;
    while (lo < hi) {
        int mid = (lo + hi) >> 1;
        if (a[mid] < key) lo = mid + 1;
        else hi = mid;
    }
    return lo;
}

// one block (512 thr) per graph; 4 row-groups in parallel + LDS reduce
__global__ void __launch_bounds__(512) pool_kernel(const _Float16* __restrict__ H,
                                                   const int* __restrict__ batch,
                                                   float* __restrict__ pooled, int N) {
    __shared__ int range[2];
    __shared__ float part[4][128];
    int g = blockIdx.x;
    int t = threadIdx.x;
    int j = t & 127, rg = t >> 7;
    if (t < 2) range[t] = lower_bound_i(batch, N, g + t);
    __syncthreads();
    int lo = range[0], hi = range[1];
    float s = 0.f;
    for (int v = lo + rg; v < hi; v += 4) s += (float)H[(size_t)v * 128 + j];
    part[rg][j] = s;
    __syncthreads();
    if (rg == 0) {
        float tot = part[0][j] + part[1][j] + part[2][j] + part[3][j];
        pooled[g * 128 + j] = tot / fmaxf((float)(hi - lo), 1.0f);
    }
}

// one block (128 thr) per graph: relu(pooled@fc1+b1) @ fc2 + b2 -> log_softmax(2)
__global__ void head_kernel(const float* __restrict__ pooled, const float* __restrict__ fc1w,
                            const float* __restrict__ fc1b, const float* __restrict__ fc2w,
                            const float* __restrict__ fc2b, float* __restrict__ out) {
    __shared__ float p[128];
    __shared__ float r0[128], r1[128];
    int g = blockIdx.x;
    int j = threadIdx.x;
    p[j] = pooled[g * 128 + j];
    __syncthreads();
    float acc = fc1b[j];
#pragma unroll 8
    for (int k = 0; k < 128; ++k) acc = fmaf(p[k], fc1w[k * 128 + j], acc);
    float gv = fmaxf(acc, 0.f);
    r0[j] = gv * fc2w[j * 2 + 0];
    r1[j] = gv * fc2w[j * 2 + 1];
    __syncthreads();
    for (int s = 64; s > 0; s >>= 1) {
        if (j < s) {
            r0[j] += r0[j + s];
            r1[j] += r1[j + s];
        }
        __syncthreads();
    }
    if (j == 0) {
        float l0 = r0[0] + fc2b[0];
        float l1 = r1[0] + fc2b[1];
        float m = fmaxf(l0, l1);
        float lse = m + logf(expf(l0 - m) + expf(l1 - m));
        out[g * 2 + 0] = l0 - lse;
        out[g * 2 + 1] = l1 - lse;
    }
}

extern "C" void kernel_launch(void* const* d_in, const int* in_sizes, int n_in,
                              void* d_out, int out_size, void* d_ws, size_t ws_size,
                              hipStream_t stream) {
    const float* x    = (const float*)d_in[0];
    const int* edges  = (const int*)d_in[1];
    const int* batch  = (const int*)d_in[2];
    const float* W1   = (const float*)d_in[3];
    const float* b1   = (const float*)d_in[4];
    const float* W2   = (const float*)d_in[5];
    const float* b2   = (const float*)d_in[6];
    const float* fc1w = (const float*)d_in[7];
    const float* fc1b = (const float*)d_in[8];
    const float* fc2w = (const float*)d_in[9];
    const float* fc2b = (const float*)d_in[10];
    float* out = (float*)d_out;

    int N = in_sizes[2];        // 100000
    int E = in_sizes[1] / 2;    // 1600000
    int G = out_size / 2;       // 1024
    int nb = (N + BNODES - 1) / BNODES;   // 196
    int nA = (E + CHUNK - 1) / CHUNK;     // 391

    char* ws = (char*)d_ws;
    size_t off = 0;
    auto alloc = [&](size_t bytes) -> char* {
        char* ptr = ws + off;
        off += (bytes + 255) & ~(size_t)255;
        return ptr;
    };
    int* gcur          = (int*)alloc((size_t)nb * 4);
    int* binned        = (int*)alloc((size_t)nb * CAPB * 4);
    int* rowptr        = (int*)alloc((size_t)(N + 1) * 4);
    float* dis         = (float*)alloc((size_t)N * 4);
    int* gcursor       = (int*)alloc((size_t)nb * BNODES * 4);
    int* csr           = (int*)alloc((size_t)E * 4);
    _Float16* Wt1      = (_Float16*)alloc(128 * 128 * 2);
    _Float16* Wt2      = (_Float16*)alloc(128 * 128 * 2);
    unsigned char* buf8 = (unsigned char*)alloc((size_t)N * D_FEAT);
    _Float16* bufH     = (_Float16*)alloc((size_t)N * D_FEAT * 2);
    float* pooled      = (float*)alloc((size_t)G * D_FEAT * 4);

    hipMemsetAsync(gcur, 0, (size_t)nb * 4, stream);

    binA_kernel<<<nA, 256, 0, stream>>>(edges, gcur, binned, E, nb);
    binB1_kernel<<<nb, 256, 0, stream>>>(binned, gcur, dis, rowptr, gcursor, N, E, nb);
    binB2_kernel<<<nb, 256, 0, stream>>>(binned, gcur, gcursor, csr, nb);
    wprep_kernel<<<64, 256, 0, stream>>>(W1, W2, Wt1, Wt2);

    int gAgg = (N * 64 + 255) / 256;
    int gGemm = (N + 63) / 64;
    gemm_mfma_kernel<false><<<gGemm, 256, 0, stream>>>((const void*)x, Wt1, dis, buf8, N);
    agg_kernel<<<gAgg, 256, 0, stream>>>(buf8, rowptr, csr, dis, b1, bufH, N);
    gemm_mfma_kernel<true><<<gGemm, 256, 0, stream>>>((const void*)bufH, Wt2, dis, buf8, N);
    agg_kernel<<<gAgg, 256, 0, stream>>>(buf8, rowptr, csr, dis, b2, bufH, N);
    pool_kernel<<<G, 512, 0, stream>>>(bufH, batch, pooled, N);
    head_kernel<<<G, 128, 0, stream>>>(pooled, fc1w, fc1b, fc2w, fc2b, out);
}

// Round 13
// 266.531 us; speedup vs baseline: 1.2558x; 1.0581x over previous
//
#include <hip/hip_runtime.h>
#include <hip/hip_fp16.h>
#include <math.h>

// GCN: h1 = relu(Agg(x@W1)+b1); h2 = relu(Agg(h1@W2)+b2); pooled = segment_mean(h2);
// out = log_softmax(relu(pooled@fc1+b)@fc2+b)
// buf8[s] = fp8(dis[s] * (x@W)[s]); Agg(v) = relu(dis[v]*(row_v + sum row_s) + b).
// CSR: fixed per-bucket stride (PCAP); per-node lists padded to multiple of 16 with
// dummy src=N -> zero row; agg is one uniform 8-deep loop. Node extents via explicit
// rowbeg/rowend (rowptr[v+1] is WRONG at bucket boundaries with strided layout —
// round-12 crash: last node per bucket walked unwritten poison slots).

#define D_FEAT 128
#define BSHIFT 9
#define BNODES 512
#define CHUNK 4096
#define CAPB 16384
#define PCAP 16384
#define CAP 10240

using half8   = __attribute__((ext_vector_type(8))) _Float16;
using half4   = __attribute__((ext_vector_type(4))) _Float16;
using floatx4 = __attribute__((ext_vector_type(4))) float;
using floatx2 = __attribute__((ext_vector_type(2))) float;

// ---- single-pass binning: binned[b*CAPB + pos] = (dstlow<<17)|src ----
__global__ void __launch_bounds__(256) binA_kernel(const int* __restrict__ edges,
                                                   int* __restrict__ gcur,
                                                   int* __restrict__ binned, int E, int nb) {
    __shared__ int h[256];
    __shared__ int cur[256];
    __shared__ int base[256];
    int t = threadIdx.x;
    int c0 = blockIdx.x * CHUNK;
    int sv[CHUNK / 256], bv[CHUNK / 256];
    int i0 = c0 + t * (CHUNK / 256);
    if (i0 + (CHUNK / 256) <= E) {
#pragma unroll
        for (int k = 0; k < CHUNK / 256; k += 4) {
            int4 s4 = *(const int4*)&edges[i0 + k];
            int4 d4 = *(const int4*)&edges[E + i0 + k];
            bv[k + 0] = d4.x >> BSHIFT; sv[k + 0] = ((d4.x & (BNODES - 1)) << 17) | s4.x;
            bv[k + 1] = d4.y >> BSHIFT; sv[k + 1] = ((d4.y & (BNODES - 1)) << 17) | s4.y;
            bv[k + 2] = d4.z >> BSHIFT; sv[k + 2] = ((d4.z & (BNODES - 1)) << 17) | s4.z;
            bv[k + 3] = d4.w >> BSHIFT; sv[k + 3] = ((d4.w & (BNODES - 1)) << 17) | s4.w;
        }
    } else {
#pragma unroll
        for (int k = 0; k < CHUNK / 256; ++k) {
            int i = i0 + k;
            if (i < E) {
                int s = edges[i], d = edges[E + i];
                bv[k] = d >> BSHIFT;
                sv[k] = ((d & (BNODES - 1)) << 17) | s;
            } else bv[k] = -1;
        }
    }
    h[t] = 0;
    __syncthreads();
#pragma unroll
    for (int k = 0; k < CHUNK / 256; ++k)
        if (bv[k] >= 0) atomicAdd(&h[bv[k]], 1);
    __syncthreads();
    if (t < nb && h[t] > 0) base[t] = atomicAdd(&gcur[t], h[t]);
    cur[t] = 0;
    __syncthreads();
#pragma unroll
    for (int k = 0; k < CHUNK / 256; ++k)
        if (bv[k] >= 0) {
            int b = bv[k];
            int r = atomicAdd(&cur[b], 1);
            int pos = base[b] + r;
            if (pos < CAPB) binned[b * CAPB + pos] = sv[k];
        }
}

// ---- binB (fused): per bucket: hist -> dis/rowbeg/rowend, scatter reals, pad dummies ----
__global__ void __launch_bounds__(256) binB_kernel(const int* __restrict__ binned,
                                                   const int* __restrict__ gcur,
                                                   float* __restrict__ dis,
                                                   int* __restrict__ rowbeg,
                                                   int* __restrict__ rowend,
                                                   int* __restrict__ csr,
                                                   int N, int nb) {
    __shared__ int hist[BNODES];
    __shared__ int cur[BNODES];
    __shared__ int pend[BNODES];
    __shared__ int sdata[256];
    __shared__ int vals[CAP];
    int t = threadIdx.x;
    int b = blockIdx.x;
    int node0 = b << BSHIFT;
    int cnt = gcur[b];
    const int* bin = binned + (size_t)b * CAPB;
    hist[t] = 0; hist[t + 256] = 0;
    __syncthreads();
    for (int i = t; i < cnt; i += 256) {
        int v = bin[i];
        if (i < CAP) vals[i] = v;
        atomicAdd(&hist[v >> 17], 1);
    }
    __syncthreads();
    int a0 = hist[2 * t], a1 = hist[2 * t + 1];
    int p0sz = (a0 + 15) & ~15, p1sz = (a1 + 15) & ~15;   // pad to multiple of 16
    int pair = p0sz + p1sz;
    sdata[t] = pair;
    __syncthreads();
    for (int d = 1; d < 256; d <<= 1) {
        int u = (t >= d) ? sdata[t - d] : 0;
        __syncthreads();
        sdata[t] += u;
        __syncthreads();
    }
    int excl = sdata[t] - pair;
    int q0 = b * PCAP + excl, q1 = q0 + p0sz;
    cur[2 * t] = q0;
    cur[2 * t + 1] = q1;
    pend[2 * t] = q1;
    pend[2 * t + 1] = q1 + p1sz;
    int n0 = node0 + 2 * t, n1 = node0 + 2 * t + 1;
    if (n0 < N) {
        rowbeg[n0] = q0; rowend[n0] = q1;
        dis[n0] = rsqrtf((float)a0 + 1.0f);
    }
    if (n1 < N) {
        rowbeg[n1] = q1; rowend[n1] = q1 + p1sz;
        dis[n1] = rsqrtf((float)a1 + 1.0f);
    }
    __syncthreads();
    for (int i = t; i < cnt; i += 256) {
        int v = (i < CAP) ? vals[i] : bin[i];
        int p = atomicAdd(&cur[v >> 17], 1);
        csr[p] = v & 0x1FFFF;
    }
    __syncthreads();
    for (int i = t; i < BNODES; i += 256) {
        int e = pend[i];
        for (int p = cur[i]; p < e; ++p) csr[p] = N;   // dummy -> zero row
    }
}

// W transpose + fp32->fp16; also zeroes buf8 row N (dummy target)
__global__ void wprep_kernel(const float* __restrict__ W1, const float* __restrict__ W2,
                             _Float16* __restrict__ Wt1, _Float16* __restrict__ Wt2,
                             unsigned int* __restrict__ zrow) {
    int i = blockIdx.x * blockDim.x + threadIdx.x;
    int n = i >> 7, k = i & 127;
    Wt1[i] = (_Float16)W1[k * 128 + n];
    Wt2[i] = (_Float16)W2[k * 128 + n];
    if (i < 32) zrow[i] = 0u;
}

// Y8[row,:] = fp8_e4m3( dis[row] * (X[row,:] @ W) ) via fp16 MFMA.
template <bool HALF_IN>
__global__ void __launch_bounds__(256) gemm_mfma_kernel(const void* __restrict__ Xv,
                                                        const _Float16* __restrict__ WtG,
                                                        const float* __restrict__ dis,
                                                        unsigned char* __restrict__ Y8, int N) {
    __shared__ _Float16 wt[128][136];
    int t = threadIdx.x;
    int row0 = blockIdx.x * 64;

#pragma unroll
    for (int i = 0; i < 8; ++i) {
        int c = t + i * 256;
        int r = c >> 4, c8 = (c & 15) * 8;
        *(half8*)&wt[r][c8] = *(const half8*)&WtG[r * 128 + c8];
    }

    int wave = t >> 6, lane = t & 63;
    int m = lane & 15, quad = lane >> 4;
    int grow = row0 + wave * 16 + m;

    half8 a[4];
    if (grow < N) {
        if (HALF_IN) {
            const _Float16* Xp = (const _Float16*)Xv;
#pragma unroll
            for (int k = 0; k < 4; ++k)
                a[k] = *(const half8*)&Xp[(size_t)grow * 128 + k * 32 + quad * 8];
        } else {
            const float* Xp = (const float*)Xv;
#pragma unroll
            for (int k = 0; k < 4; ++k) {
                float4 v0 = *(const float4*)&Xp[(size_t)grow * 128 + k * 32 + quad * 8];
                float4 v1 = *(const float4*)&Xp[(size_t)grow * 128 + k * 32 + quad * 8 + 4];
                a[k] = (half8){(_Float16)v0.x, (_Float16)v0.y, (_Float16)v0.z, (_Float16)v0.w,
                               (_Float16)v1.x, (_Float16)v1.y, (_Float16)v1.z, (_Float16)v1.w};
            }
        }
    } else {
#pragma unroll
        for (int k = 0; k < 4; ++k) a[k] = (half8){};
    }
    __syncthreads();

    floatx4 acc[8];
#pragma unroll
    for (int nt = 0; nt < 8; ++nt) acc[nt] = (floatx4){0.f, 0.f, 0.f, 0.f};
#pragma unroll
    for (int nt = 0; nt < 8; ++nt) {
#pragma unroll
        for (int k = 0; k < 4; ++k) {
            half8 bfr = *(const half8*)&wt[nt * 16 + m][k * 32 + quad * 8];
            acc[nt] = __builtin_amdgcn_mfma_f32_16x16x32_f16(a[k], bfr, acc[nt], 0, 0, 0);
        }
    }
    int orow = row0 + wave * 16 + quad * 4;
#pragma unroll
    for (int r = 0; r < 4; ++r) {
        int row = orow + r;
        if (row < N) {
            float dr = dis[row];
#pragma unroll
            for (int nt = 0; nt < 8; ++nt) {
                float v = acc[nt][r] * dr;
                unsigned char q =
                    (unsigned char)(__builtin_amdgcn_cvt_pk_fp8_f32(v, v, 0, false) & 0xff);
                Y8[(size_t)row * 128 + nt * 16 + m] = q;
            }
        }
    }
}

// One wave per dst node over pre-scaled fp8 rows; half-wave per edge, plain adds.
// CSR padded to multiple of 16 per node (dummies -> zero row): single uniform loop.
__global__ void __launch_bounds__(256) agg_kernel(const unsigned char* __restrict__ H8,
                                                  const int* __restrict__ rowbeg,
                                                  const int* __restrict__ rowend,
                                                  const int* __restrict__ csr,
                                                  const float* __restrict__ dis,
                                                  const float* __restrict__ bias,
                                                  _Float16* __restrict__ out, int N) {
    int v = (blockIdx.x * blockDim.x + threadIdx.x) >> 6;
    int lane = threadIdx.x & 63;
    if (v >= N) return;
    int half = lane >> 5, sl = lane & 31;
    int r0 = rowbeg[v], r1 = rowend[v];
    float dv = dis[v];
    unsigned fo = (unsigned)(sl << 2);

    floatx2 a01, a23;
    {   // self row (pre-scaled): each half adds 0.5x, sums to 1x after combine
        unsigned int u = *(const unsigned int*)(H8 + (((unsigned)v << 7) | fo));
        floatx2 lo = __builtin_amdgcn_cvt_pk_f32_fp8(u, false);
        floatx2 hi = __builtin_amdgcn_cvt_pk_f32_fp8(u, true);
        floatx2 hf = {0.5f, 0.5f};
        a01 = hf * lo;
        a23 = hf * hi;
    }
#define ACC(uu)                                                         \
        {                                                               \
            a01 += __builtin_amdgcn_cvt_pk_f32_fp8(uu, false);          \
            a23 += __builtin_amdgcn_cvt_pk_f32_fp8(uu, true);           \
        }
    for (int e = r0 + half; e + 14 < r1; e += 16) {   // uniform: 8 edges per half
        int s0 = csr[e],      s1 = csr[e + 2],  s2 = csr[e + 4],  s3 = csr[e + 6];
        int s4 = csr[e + 8],  s5 = csr[e + 10], s6 = csr[e + 12], s7 = csr[e + 14];
        unsigned int u0 = *(const unsigned int*)(H8 + (((unsigned)s0 << 7) | fo));
        unsigned int u1 = *(const unsigned int*)(H8 + (((unsigned)s1 << 7) | fo));
        unsigned int u2 = *(const unsigned int*)(H8 + (((unsigned)s2 << 7) | fo));
        unsigned int u3 = *(const unsigned int*)(H8 + (((unsigned)s3 << 7) | fo));
        unsigned int u4 = *(const unsigned int*)(H8 + (((unsigned)s4 << 7) | fo));
        unsigned int u5 = *(const unsigned int*)(H8 + (((unsigned)s5 << 7) | fo));
        unsigned int u6 = *(const unsigned int*)(H8 + (((unsigned)s6 << 7) | fo));
        unsigned int u7 = *(const unsigned int*)(H8 + (((unsigned)s7 << 7) | fo));
        ACC(u0) ACC(u1) ACC(u2) ACC(u3) ACC(u4) ACC(u5) ACC(u6) ACC(u7)
    }
#undef ACC
    a01[0] += __shfl_xor(a01[0], 32, 64);
    a01[1] += __shfl_xor(a01[1], 32, 64);
    a23[0] += __shfl_xor(a23[0], 32, 64);
    a23[1] += __shfl_xor(a23[1], 32, 64);
    if (half == 0) {
        float4 b = *(const float4*)&bias[sl * 4];
        half4 o = {(_Float16)fmaxf(dv * a01[0] + b.x, 0.f),
                   (_Float16)fmaxf(dv * a01[1] + b.y, 0.f),
                   (_Float16)fmaxf(dv * a23[0] + b.z, 0.f),
                   (_Float16)fmaxf(dv * a23[1] + b.w, 0.f)};
        *(half4*)&out[(size_t)v * 128 + sl * 4] = o;
    }
}

__device__ __forceinline__ int lower_bound_i(const int* a, int n, int key) {
    int lo = 0, hi = n;
    while (lo < hi) {
        int mid = (lo + hi) >> 1;
        if (a[mid] < key) lo = mid + 1;
        else hi = mid;
    }
    return lo;
}

// Fused pool + head: one block (512 thr) per graph.
__global__ void __launch_bounds__(512) poolhead_kernel(const _Float16* __restrict__ H,
                                                       const int* __restrict__ batch,
                                                       const float* __restrict__ fc1w,
                                                       const float* __restrict__ fc1b,
                                                       const float* __restrict__ fc2w,
                                                       const float* __restrict__ fc2b,
                                                       float* __restrict__ out, int N) {
    __shared__ int range[2];
    __shared__ float part[4][128];
    __shared__ float p[128];
    __shared__ float r0s[128], r1s[128];
    int g = blockIdx.x;
    int t = threadIdx.x;
    int j = t & 127, rg = t >> 7;
    if (t < 2) range[t] = lower_bound_i(batch, N, g + t);
    __syncthreads();
    int lo = range[0], hi = range[1];
    float s = 0.f;
    for (int v = lo + rg; v < hi; v += 4) s += (float)H[(size_t)v * 128 + j];
    part[rg][j] = s;
    __syncthreads();
    if (rg == 0) {
        float tot = part[0][j] + part[1][j] + part[2][j] + part[3][j];
        p[j] = tot / fmaxf((float)(hi - lo), 1.0f);
    }
    __syncthreads();
    if (t < 128) {
        float acc = fc1b[t];
#pragma unroll 8
        for (int k = 0; k < 128; ++k) acc = fmaf(p[k], fc1w[k * 128 + t], acc);
        float gv = fmaxf(acc, 0.f);
        r0s[t] = gv * fc2w[t * 2 + 0];
        r1s[t] = gv * fc2w[t * 2 + 1];
    }
    __syncthreads();
    for (int st = 64; st > 0; st >>= 1) {
        if (t < st) {
            r0s[t] += r0s[t + st];
            r1s[t] += r1s[t + st];
        }
        __syncthreads();
    }
    if (t == 0) {
        float l0 = r0s[0] + fc2b[0];
        float l1 = r1s[0] + fc2b[1];
        float m = fmaxf(l0, l1);
        float lse = m + logf(expf(l0 - m) + expf(l1 - m));
        out[g * 2 + 0] = l0 - lse;
        out[g * 2 + 1] = l1 - lse;
    }
}

extern "C" void kernel_launch(void* const* d_in, const int* in_sizes, int n_in,
                              void* d_out, int out_size, void* d_ws, size_t ws_size,
                              hipStream_t stream) {
    const float* x    = (const float*)d_in[0];
    const int* edges  = (const int*)d_in[1];
    const int* batch  = (const int*)d_in[2];
    const float* W1   = (const float*)d_in[3];
    const float* b1   = (const float*)d_in[4];
    const float* W2   = (const float*)d_in[5];
    const float* b2   = (const float*)d_in[6];
    const float* fc1w = (const float*)d_in[7];
    const float* fc1b = (const float*)d_in[8];
    const float* fc2w = (const float*)d_in[9];
    const float* fc2b = (const float*)d_in[10];
    float* out = (float*)d_out;

    int N = in_sizes[2];        // 100000
    int E = in_sizes[1] / 2;    // 1600000
    int G = out_size / 2;       // 1024
    int nb = (N + BNODES - 1) / BNODES;   // 196
    int nA = (E + CHUNK - 1) / CHUNK;     // 391

    char* ws = (char*)d_ws;
    size_t off = 0;
    auto alloc = [&](size_t bytes) -> char* {
        char* ptr = ws + off;
        off += (bytes + 255) & ~(size_t)255;
        return ptr;
    };
    int* gcur          = (int*)alloc((size_t)nb * 4);
    int* binned        = (int*)alloc((size_t)nb * CAPB * 4);
    int* rowbeg        = (int*)alloc((size_t)N * 4);
    int* rowend        = (int*)alloc((size_t)N * 4);
    float* dis         = (float*)alloc((size_t)N * 4);
    int* csr           = (int*)alloc((size_t)nb * PCAP * 4);
    _Float16* Wt1      = (_Float16*)alloc(128 * 128 * 2);
    _Float16* Wt2      = (_Float16*)alloc(128 * 128 * 2);
    unsigned char* buf8 = (unsigned char*)alloc((size_t)(N + 1) * D_FEAT);  // +1 zero row
    _Float16* bufH     = (_Float16*)alloc((size_t)N * D_FEAT * 2);

    hipMemsetAsync(gcur, 0, (size_t)nb * 4, stream);

    binA_kernel<<<nA, 256, 0, stream>>>(edges, gcur, binned, E, nb);
    binB_kernel<<<nb, 256, 0, stream>>>(binned, gcur, dis, rowbeg, rowend, csr, N, nb);
    wprep_kernel<<<64, 256, 0, stream>>>(W1, W2, Wt1, Wt2,
                                         (unsigned int*)(buf8 + (size_t)N * D_FEAT));

    int gAgg = (N * 64 + 255) / 256;
    int gGemm = (N + 63) / 64;
    gemm_mfma_kernel<false><<<gGemm, 256, 0, stream>>>((const void*)x, Wt1, dis, buf8, N);
    agg_kernel<<<gAgg, 256, 0, stream>>>(buf8, rowbeg, rowend, csr, dis, b1, bufH, N);
    gemm_mfma_kernel<true><<<gGemm, 256, 0, stream>>>((const void*)bufH, Wt2, dis, buf8, N);
    agg_kernel<<<gAgg, 256, 0, stream>>>(buf8, rowbeg, rowend, csr, dis, b2, bufH, N);
    poolhead_kernel<<<G, 512, 0, stream>>>(bufH, batch, fc1w, fc1b, fc2w, fc2b, out, N);
}